// Round 3
// baseline (341.311 us; speedup 1.0000x reference)
//
#include <hip/hip_runtime.h>

#define Bn 512
#define Tn 512
#define Cn 64

// Inputs (setup_inputs order):
// 0: emissions (B,T,C) f32   1: tags (B,T) i32   2: mask (B,T) i32
// 3: transitions (C,C) f32   4: start_transitions (C) f32   5: end_transitions (C) f32
// Output: scalar f32 = mean_b(log_denominator - log_numerator)

__device__ __forceinline__ float2 fma2(const float2 a, const float2 b, const float2 c) {
    float2 r;
    r.x = fmaf(a.x, b.x, c.x);
    r.y = fmaf(a.y, b.y, c.y);
    return r;
}

template <int CTRL>
__device__ __forceinline__ float add_dpp(const float v) {
    const int o = __builtin_amdgcn_update_dpp(__float_as_int(v), __float_as_int(v),
                                              CTRL, 0xF, 0xF, false);
    return v + __int_as_float(o);
}

template <int CTRL>
__device__ __forceinline__ float fmax_dpp(const float v) {
    const int o = __builtin_amdgcn_update_dpp(__float_as_int(v), __float_as_int(v),
                                              CTRL, 0xF, 0xF, false);
    return fmaxf(v, __int_as_float(o));
}

// Validated round-2 network: quad xor1, quad xor2, half-mirror, mirror,
// bcast15, bcast31 -> lane 63 holds the max; readlane broadcasts.
__device__ __forceinline__ float wave_max64(float v) {
    v = fmax_dpp<0x0B1>(v);
    v = fmax_dpp<0x04E>(v);
    v = fmax_dpp<0x141>(v);
    v = fmax_dpp<0x140>(v);
    v = fmax_dpp<0x142>(v);
    v = fmax_dpp<0x143>(v);
    return __int_as_float(__builtin_amdgcn_readlane(__float_as_int(v), 63));
}

// 3-stage in-row sum over b (lane low 3 bits). After quad xor1+xor2 every
// lane holds its quad sum; row_half_mirror (reversal within 8) then maps each
// lane to the OTHER quad of its octet -> adds give the full 8-lane (b) sum on
// all 8 lanes. Pure VALU latency, no LDS pipe.
__device__ __forceinline__ float sum_over_b(float v) {
    v = add_dpp<0x0B1>(v);  // quad_perm [1,0,3,2] : xor 1
    v = add_dpp<0x04E>(v);  // quad_perm [2,3,0,1] : xor 2
    v = add_dpp<0x141>(v);  // row_half_mirror     : other quad
    return v;
}

// One wave per batch chain. Lane = a*8+b (a = lane>>3 output block,
// b = lane&7 input block). Linear-space recurrence, renorm every 4 steps:
//   P[y]   = sum_x alpha[8b+x] * expT[8b+x][8a+y]     (64 reg-resident FMAs)
//   s[j]   = (sum_b P)[j] * exp(emit[t][j])           (3 DPP stages + mul)
//   alpha' = transpose a<->b via 8x ds_bpermute       (one LDS-crossbar trip)
__global__ __launch_bounds__(64) void crf_fused_kernel(
    const float* __restrict__ emissions,
    const int*   __restrict__ tags,
    const int*   __restrict__ mask,
    const float* __restrict__ transitions,
    const float* __restrict__ start_t,
    const float* __restrict__ end_t,
    float*       __restrict__ out)
{
    const int bt   = blockIdx.x;
    const int lane = threadIdx.x;
    const int bsub = lane & 7;   // input block
    const int asub = lane >> 3;  // output block

    const float* emB = emissions + (size_t)bt * Tn * Cn;
    const int*   mk  = mask + bt * Tn;
    const int*   tg  = tags + bt * Tn;

    // ---------------- numerator (joint score), lanes stride over T ---------
    float nsum = 0.f;
    int   mcnt = 0;
    for (int t = lane; t < Tn; t += 64) {
        const int tag_t = tg[t];
        const int m_t   = mk[t];
        mcnt += m_t;
        if (t >= 1 && m_t) {
            const int tag_p = tg[t - 1];
            nsum += transitions[tag_p * Cn + tag_t] + emB[t * Cn + tag_t];
        }
    }
#pragma unroll
    for (int off = 32; off > 0; off >>= 1) {
        nsum += __shfl_xor(nsum, off, 64);
        mcnt += __shfl_xor(mcnt, off, 64);
    }

    // ---------------- expT 8x8 block per lane: expT[8b+x][8a+y] ------------
    float2 A2[8][4];
#pragma unroll
    for (int x = 0; x < 8; ++x) {
        const float* rowp = transitions + (8 * bsub + x) * Cn + 8 * asub;
#pragma unroll
        for (int yy = 0; yy < 4; ++yy) {
            A2[x][yy].x = __expf(rowp[2 * yy + 0]);
            A2[x][yy].y = __expf(rowp[2 * yy + 1]);
        }
    }

    // ---------------- t = 0: alpha in input layout (block b) ---------------
    float a_in[8];
    float log_scale;
    {
        float lp[8];
        float mloc = -3.4e38f;
#pragma unroll
        for (int y = 0; y < 8; ++y) {
            lp[y] = start_t[8 * bsub + y] + emB[8 * bsub + y];
            mloc = fmaxf(mloc, lp[y]);
        }
        const float m0 = wave_max64(mloc);  // replication over a harmless
        log_scale = m0;
#pragma unroll
        for (int y = 0; y < 8; ++y) a_in[y] = __expf(lp[y] - m0);
    }

    // bpermute source lane: (b*8 + a), byte address
    const int swap_addr = (((bsub << 3) | asub) << 2);

    // Prefetch group 0 (t = 1..4): emissions columns 8a..8a+7 + scalar mask.
    float4 cur_e[4][2];
    int    cur_m[4];
#pragma unroll
    for (int k = 0; k < 4; ++k) {
        const float* p = emB + (size_t)(1 + k) * Cn + 8 * asub;
        cur_e[k][0] = *(const float4*)p;
        cur_e[k][1] = *(const float4*)(p + 4);
        cur_m[k]    = mk[1 + k];
    }

    for (int g = 0; g < 128; ++g) {
        // Prefetch next group (4 steps ahead covers HBM latency).
        float4 nxt_e[4][2];
        int    nxt_m[4];
#pragma unroll
        for (int k = 0; k < 4; ++k) {
            const int t = 4 * g + 5 + k;
            if (t < Tn) {
                const float* p = emB + (size_t)t * Cn + 8 * asub;
                nxt_e[k][0] = *(const float4*)p;
                nxt_e[k][1] = *(const float4*)(p + 4);
                nxt_m[k]    = mk[t];
            } else {
                nxt_e[k][0] = make_float4(0.f, 0.f, 0.f, 0.f);
                nxt_e[k][1] = make_float4(0.f, 0.f, 0.f, 0.f);
                nxt_m[k]    = 0;
            }
        }

#pragma unroll
        for (int k = 0; k < 4; ++k) {
            const int t = 4 * g + 1 + k;
            if (t < Tn) {
                // exp(emissions) for this step's output block (off dep-chain).
                float ex[8];
                ex[0] = __expf(cur_e[k][0].x); ex[1] = __expf(cur_e[k][0].y);
                ex[2] = __expf(cur_e[k][0].z); ex[3] = __expf(cur_e[k][0].w);
                ex[4] = __expf(cur_e[k][1].x); ex[5] = __expf(cur_e[k][1].y);
                ex[6] = __expf(cur_e[k][1].z); ex[7] = __expf(cur_e[k][1].w);

                // 8x8 block mat-vec: 32 packed FMAs.
                float2 P2[4];
                P2[0] = make_float2(0.f, 0.f); P2[1] = make_float2(0.f, 0.f);
                P2[2] = make_float2(0.f, 0.f); P2[3] = make_float2(0.f, 0.f);
#pragma unroll
                for (int x = 0; x < 8; ++x) {
                    const float2 av = make_float2(a_in[x], a_in[x]);
                    P2[0] = fma2(av, A2[x][0], P2[0]);
                    P2[1] = fma2(av, A2[x][1], P2[1]);
                    P2[2] = fma2(av, A2[x][2], P2[2]);
                    P2[3] = fma2(av, A2[x][3], P2[3]);
                }
                float s[8] = { P2[0].x, P2[0].y, P2[1].x, P2[1].y,
                               P2[2].x, P2[2].y, P2[3].x, P2[3].y };

                // Reduce over b (3 DPP stages), then emission multiply.
#pragma unroll
                for (int i = 0; i < 8; ++i) s[i] = sum_over_b(s[i]);
#pragma unroll
                for (int i = 0; i < 8; ++i) s[i] *= ex[i];

                // Transpose a<->b: pull s[y] from lane (b*8+a).
                float an[8];
#pragma unroll
                for (int i = 0; i < 8; ++i)
                    an[i] = __int_as_float(
                        __builtin_amdgcn_ds_bpermute(swap_addr, __float_as_int(s[i])));

                // mask==0: carry previous alpha (wave-uniform condition).
                if (!cur_m[k]) {
#pragma unroll
                    for (int i = 0; i < 8; ++i) an[i] = a_in[i];
                }

                // Renorm every 4th step (post-select; uniform scale exact).
                if (k == 3) {
                    float mloc = an[0];
#pragma unroll
                    for (int i = 1; i < 8; ++i) mloc = fmaxf(mloc, an[i]);
                    const float mx = wave_max64(mloc);
                    const float r  = __builtin_amdgcn_rcpf(mx);
#pragma unroll
                    for (int i = 0; i < 8; ++i) an[i] *= r;
                    log_scale += __logf(mx);
                }
#pragma unroll
                for (int i = 0; i < 8; ++i) a_in[i] = an[i];
            }
        }
#pragma unroll
        for (int k = 0; k < 4; ++k) {
            cur_e[k][0] = nxt_e[k][0];
            cur_e[k][1] = nxt_e[k][1];
            cur_m[k]    = nxt_m[k];
        }
    }

    // ---------------- finalize --------------------------------------------
    // alpha is replicated 8x over a; wave-sum then * 1/8 is exact (pow2).
    float v = 0.f;
#pragma unroll
    for (int y = 0; y < 8; ++y) v += a_in[y] * __expf(end_t[8 * bsub + y]);
#pragma unroll
    for (int off = 32; off > 0; off >>= 1) v += __shfl_xor(v, off, 64);
    const float denom = log_scale + __logf(v * 0.125f);

    if (lane == 0) {
        const int last_idx = mcnt - 1;  // sum(mask) - 1
        const int t0 = tg[0];
        const int tl = tg[last_idx];
        const float num = start_t[t0] + emB[t0] + nsum + end_t[tl];
        atomicAdd(out, (denom - num) * (1.0f / Bn));
    }
}

__global__ void crf_zero_kernel(float* out) { out[0] = 0.f; }

extern "C" void kernel_launch(void* const* d_in, const int* in_sizes, int n_in,
                              void* d_out, int out_size, void* d_ws, size_t ws_size,
                              hipStream_t stream)
{
    const float* emissions   = (const float*)d_in[0];
    const int*   tags        = (const int*)d_in[1];
    const int*   mask        = (const int*)d_in[2];
    const float* transitions = (const float*)d_in[3];
    const float* start_t     = (const float*)d_in[4];
    const float* end_t       = (const float*)d_in[5];

    crf_zero_kernel<<<1, 1, 0, stream>>>((float*)d_out);
    crf_fused_kernel<<<Bn, Cn, 0, stream>>>(emissions, tags, mask, transitions,
                                            start_t, end_t, (float*)d_out);
}

// Round 4
// 234.962 us; speedup vs baseline: 1.4526x; 1.4526x over previous
//
#include <hip/hip_runtime.h>

#define Bn 512
#define Tn 512
#define Cn 64

// Inputs (setup_inputs order):
// 0: emissions (B,T,C) f32   1: tags (B,T) i32   2: mask (B,T) i32
// 3: transitions (C,C) f32   4: start_transitions (C) f32   5: end_transitions (C) f32
// Output: scalar f32 = mean_b(log_denominator - log_numerator)

template <int CTRL>
__device__ __forceinline__ float fmax_dpp(const float v) {
    const int o = __builtin_amdgcn_update_dpp(__float_as_int(v), __float_as_int(v),
                                              CTRL, 0xF, 0xF, false);
    return fmaxf(v, __int_as_float(o));
}

// Validated (R2/R3) wave64 max: quad xor1, quad xor2, half-mirror, mirror,
// bcast15, bcast31 -> lane 63 holds the max; readlane broadcasts.
__device__ __forceinline__ float wave_max64(float v) {
    v = fmax_dpp<0x0B1>(v);
    v = fmax_dpp<0x04E>(v);
    v = fmax_dpp<0x141>(v);
    v = fmax_dpp<0x140>(v);
    v = fmax_dpp<0x142>(v);
    v = fmax_dpp<0x143>(v);
    return __int_as_float(__builtin_amdgcn_readlane(__float_as_int(v), 63));
}

// One wave per batch chain. Lane j owns class j (expT column j in 64 VGPRs,
// its own alpha[j] in a_self). Linear-space recurrence, renorm every 4 steps.
// KEY (R4): alpha is wave-uniform -> broadcast via 64x v_readlane into SGPRs
// (pure VALU issue, no LDS pipe, no memory latency) and dot via v_fma with
// one SGPR operand. No __shared__, no ds_* in the main loop.
__global__ __launch_bounds__(64) void crf_fused_kernel(
    const float* __restrict__ emissions,
    const int*   __restrict__ tags,
    const int*   __restrict__ mask,
    const float* __restrict__ transitions,
    const float* __restrict__ start_t,
    const float* __restrict__ end_t,
    float*       __restrict__ out)
{
    const int bt = blockIdx.x;
    const int j  = threadIdx.x;  // class index

    const float* em  = emissions + (size_t)bt * Tn * Cn + j;
    const float* em0 = emissions + (size_t)bt * Tn * Cn;
    const int*   mk  = mask + bt * Tn;
    const int*   tg  = tags + bt * Tn;

    // ---------------- numerator (joint score), lanes stride over T ---------
    float nsum = 0.f;
    int   mcnt = 0;
    for (int t = j; t < Tn; t += 64) {
        const int tag_t = tg[t];
        const int m_t   = mk[t];
        mcnt += m_t;
        if (t >= 1 && m_t) {
            const int tag_p = tg[t - 1];
            nsum += transitions[tag_p * Cn + tag_t] + em0[t * Cn + tag_t];
        }
    }
#pragma unroll
    for (int off = 32; off > 0; off >>= 1) {
        nsum += __shfl_xor(nsum, off, 64);
        mcnt += __shfl_xor(mcnt, off, 64);
    }

    // ---------------- expT column j in registers ---------------------------
    float expTcol[Cn];
#pragma unroll
    for (int i = 0; i < Cn; ++i) expTcol[i] = __expf(transitions[i * Cn + j]);

    // ---------------- t = 0 ------------------------------------------------
    float lp0 = start_t[j] + em[0];
    const float m0 = wave_max64(lp0);
    float log_scale = m0;                  // wave-uniform
    float a_self = __expf(lp0 - m0);       // lane j holds alpha[j]

    // Prefetch group 0 (t = 1..4) emissions + mask.
    float cur_e[4];
    int   cur_m[4];
#pragma unroll
    for (int k = 0; k < 4; ++k) {
        cur_e[k] = em[(size_t)(1 + k) * Cn];
        cur_m[k] = mk[1 + k];
    }

    for (int g = 0; g < 128; ++g) {
        // Prefetch next group (4 steps ahead covers HBM/L2 latency).
        float nxt_e[4];
        int   nxt_m[4];
#pragma unroll
        for (int k = 0; k < 4; ++k) {
            const int t = 4 * g + 5 + k;
            nxt_e[k] = (t < Tn) ? em[(size_t)t * Cn] : 0.f;
            nxt_m[k] = (t < Tn) ? mk[t] : 0;
        }
        // exp() of this group's emissions, off the critical path.
        float ex[4];
#pragma unroll
        for (int k = 0; k < 4; ++k) ex[k] = __expf(cur_e[k]);

#pragma unroll
        for (int k = 0; k < 4; ++k) {
            // Broadcast alpha (wave-uniform) into scalar regs: lane i's
            // a_self is alpha[i]; readlane returns it uniformly -> SGPR.
            float au[Cn];
#pragma unroll
            for (int i = 0; i < Cn; ++i)
                au[i] = __int_as_float(
                    __builtin_amdgcn_readlane(__float_as_int(a_self), i));

            // 64-term dot, 4 accumulators: v_fma (sgpr, vgpr, vgpr).
            float acc0 = 0.f, acc1 = 0.f, acc2 = 0.f, acc3 = 0.f;
#pragma unroll
            for (int i = 0; i < Cn; i += 4) {
                acc0 = fmaf(au[i + 0], expTcol[i + 0], acc0);
                acc1 = fmaf(au[i + 1], expTcol[i + 1], acc1);
                acc2 = fmaf(au[i + 2], expTcol[i + 2], acc2);
                acc3 = fmaf(au[i + 3], expTcol[i + 3], acc3);
            }
            float s = ((acc0 + acc1) + (acc2 + acc3)) * ex[k];

            if (!cur_m[k]) s = a_self;  // mask==0: carry previous alpha

            if (k == 3) {               // renorm every 4th step (exact)
                const float mx = wave_max64(s);
                s *= __builtin_amdgcn_rcpf(mx);
                log_scale += __logf(mx);
            }
            a_self = s;
        }
#pragma unroll
        for (int k = 0; k < 4; ++k) {
            cur_e[k] = nxt_e[k];
            cur_m[k] = nxt_m[k];
        }
    }

    // ---------------- finalize --------------------------------------------
    // Last renorm at t=508; 3 raw steps -> bounded ~1e21, safe in fp32.
    float v = a_self * __expf(end_t[j]);
#pragma unroll
    for (int off = 32; off > 0; off >>= 1) v += __shfl_xor(v, off, 64);
    const float denom = log_scale + __logf(v);

    if (j == 0) {
        const int last_idx = mcnt - 1;  // sum(mask) - 1
        const int t0 = tg[0];
        const int tl = tg[last_idx];
        const float num = start_t[t0] + em0[t0] + nsum + end_t[tl];
        atomicAdd(out, (denom - num) * (1.0f / Bn));
    }
}

__global__ void crf_zero_kernel(float* out) { out[0] = 0.f; }

extern "C" void kernel_launch(void* const* d_in, const int* in_sizes, int n_in,
                              void* d_out, int out_size, void* d_ws, size_t ws_size,
                              hipStream_t stream)
{
    const float* emissions   = (const float*)d_in[0];
    const int*   tags        = (const int*)d_in[1];
    const int*   mask        = (const int*)d_in[2];
    const float* transitions = (const float*)d_in[3];
    const float* start_t     = (const float*)d_in[4];
    const float* end_t       = (const float*)d_in[5];

    crf_zero_kernel<<<1, 1, 0, stream>>>((float*)d_out);
    crf_fused_kernel<<<Bn, Cn, 0, stream>>>(emissions, tags, mask, transitions,
                                            start_t, end_t, (float*)d_out);
}

// Round 5
// 175.202 us; speedup vs baseline: 1.9481x; 1.3411x over previous
//
#include <hip/hip_runtime.h>

#define Bn 512
#define Tn 512
#define Cn 64

// Inputs (setup_inputs order):
// 0: emissions (B,T,C) f32   1: tags (B,T) i32   2: mask (B,T) i32
// 3: transitions (C,C) f32   4: start_transitions (C) f32   5: end_transitions (C) f32
// Output: scalar f32 = mean_b(log_denominator - log_numerator)
//
// R5: meet-in-the-middle. Forward alpha over t=1..256 and backward beta over
// factors u=511..257 run as INDEPENDENT waves (sequential depth 511 -> 256),
// then Z = sum_i alpha_256[i]*beta_256[i] per chain in a tiny combine kernel.
// Per-step engine is R4's validated readlane-broadcast dot (no LDS in loop).

template <int CTRL>
__device__ __forceinline__ float fmax_dpp(const float v) {
    const int o = __builtin_amdgcn_update_dpp(__float_as_int(v), __float_as_int(v),
                                              CTRL, 0xF, 0xF, false);
    return fmaxf(v, __int_as_float(o));
}

// Validated wave64 max: quad xor1, quad xor2, half-mirror, mirror,
// bcast15, bcast31 -> lane 63 holds the max; readlane broadcasts.
__device__ __forceinline__ float wave_max64(float v) {
    v = fmax_dpp<0x0B1>(v);
    v = fmax_dpp<0x04E>(v);
    v = fmax_dpp<0x141>(v);
    v = fmax_dpp<0x140>(v);
    v = fmax_dpp<0x142>(v);
    v = fmax_dpp<0x143>(v);
    return __int_as_float(__builtin_amdgcn_readlane(__float_as_int(v), 63));
}

// blocks 0..511: forward chain bt (steps t=1..256) + numerator.
// blocks 512..1023: backward chain bt (factors u=511..257, 255 steps).
__global__ __launch_bounds__(64) void crf_half_kernel(
    const float* __restrict__ emissions,
    const int*   __restrict__ tags,
    const int*   __restrict__ mask,
    const float* __restrict__ transitions,
    const float* __restrict__ start_t,
    const float* __restrict__ end_t,
    float*       __restrict__ ws_alpha,   // [Bn][Cn]
    float*       __restrict__ ws_beta,    // [Bn][Cn]
    float*       __restrict__ ws_lsF,     // [Bn]
    float*       __restrict__ ws_lsB,     // [Bn]
    float*       __restrict__ ws_num)     // [Bn]
{
    const int  blk = blockIdx.x;
    const bool fwd = blk < Bn;
    const int  bt  = blk & (Bn - 1);
    const int  j   = threadIdx.x;

    const float* em  = emissions + (size_t)bt * Tn * Cn + j;
    const float* em0 = emissions + (size_t)bt * Tn * Cn;
    const int*   mk  = mask + bt * Tn;
    const int*   tg  = tags + bt * Tn;

    if (fwd) {
        // ---------------- numerator (joint score), lanes stride over T -----
        float nsum = 0.f;
        int   mcnt = 0;
        for (int t = j; t < Tn; t += 64) {
            const int tag_t = tg[t];
            const int m_t   = mk[t];
            mcnt += m_t;
            if (t >= 1 && m_t) {
                const int tag_p = tg[t - 1];
                nsum += transitions[tag_p * Cn + tag_t] + em0[t * Cn + tag_t];
            }
        }
#pragma unroll
        for (int off = 32; off > 0; off >>= 1) {
            nsum += __shfl_xor(nsum, off, 64);
            mcnt += __shfl_xor(mcnt, off, 64);
        }

        // expT column j in registers.
        float w[Cn];
#pragma unroll
        for (int i = 0; i < Cn; ++i) w[i] = __expf(transitions[i * Cn + j]);

        // t = 0.
        float lp0 = start_t[j] + em[0];
        const float m0 = wave_max64(lp0);
        float log_scale = m0;
        float a_self = __expf(lp0 - m0);     // lane j holds alpha[j]

        // Prefetch group 0 (t = 1..4).
        float cur_e[4];
        int   cur_m[4];
#pragma unroll
        for (int k = 0; k < 4; ++k) {
            cur_e[k] = em[(size_t)(1 + k) * Cn];
            cur_m[k] = mk[1 + k];
        }

        for (int g = 0; g < 64; ++g) {       // 64 groups x 4 = 256 steps
            float nxt_e[4];
            int   nxt_m[4];
#pragma unroll
            for (int k = 0; k < 4; ++k) {
                const int t = 4 * g + 5 + k;  // <= 260 < Tn, always valid
                nxt_e[k] = em[(size_t)t * Cn];
                nxt_m[k] = mk[t];
            }
            float ex[4];
#pragma unroll
            for (int k = 0; k < 4; ++k) ex[k] = __expf(cur_e[k]);

#pragma unroll
            for (int k = 0; k < 4; ++k) {
                float au[Cn];
#pragma unroll
                for (int i = 0; i < Cn; ++i)
                    au[i] = __int_as_float(
                        __builtin_amdgcn_readlane(__float_as_int(a_self), i));

                float acc0 = 0.f, acc1 = 0.f, acc2 = 0.f, acc3 = 0.f;
#pragma unroll
                for (int i = 0; i < Cn; i += 4) {
                    acc0 = fmaf(au[i + 0], w[i + 0], acc0);
                    acc1 = fmaf(au[i + 1], w[i + 1], acc1);
                    acc2 = fmaf(au[i + 2], w[i + 2], acc2);
                    acc3 = fmaf(au[i + 3], w[i + 3], acc3);
                }
                float s = ((acc0 + acc1) + (acc2 + acc3)) * ex[k];
                if (!cur_m[k]) s = a_self;
                if (k == 3) {                 // renorm every 4th step (exact)
                    const float mx = wave_max64(s);
                    s *= __builtin_amdgcn_rcpf(mx);
                    log_scale += __logf(mx);
                }
                a_self = s;
            }
#pragma unroll
            for (int k = 0; k < 4; ++k) {
                cur_e[k] = nxt_e[k];
                cur_m[k] = nxt_m[k];
            }
        }

        ws_alpha[bt * Cn + j] = a_self;       // alpha_256 (renormed at t=256)
        if (j == 0) {
            ws_lsF[bt] = log_scale;
            const int t0 = tg[0];
            const int tl = tg[mcnt - 1];
            ws_num[bt] = start_t[t0] + em0[t0] + nsum + end_t[tl];
        }
    } else {
        // expT ROW j in registers (backward dot uses rows).
        float w[Cn];
#pragma unroll
        for (int i = 0; i < Cn; ++i) w[i] = __expf(transitions[j * Cn + i]);

        // beta_511 = exp(end - max).
        float lp0 = end_t[j];
        const float m0 = wave_max64(lp0);
        float log_scale = m0;
        float b_self = __expf(lp0 - m0);      // lane j holds beta[j]

        // Step s applies factor at u = 511 - s (emissions/mask row u).
        // Prefetch group 0: s = 0..3 -> u = 511..508.
        float cur_e[4];
        int   cur_m[4];
#pragma unroll
        for (int k = 0; k < 4; ++k) {
            const int u = Tn - 1 - k;
            cur_e[k] = em[(size_t)u * Cn];
            cur_m[k] = mk[u];
        }

        for (int g = 0; g < 64; ++g) {        // steps s=4g+k, active while s<255
            float nxt_e[4];
            int   nxt_m[4];
#pragma unroll
            for (int k = 0; k < 4; ++k) {
                const int u = Tn - 5 - 4 * g - k;  // >= 252 >= 0, always valid
                nxt_e[k] = em[(size_t)u * Cn];
                nxt_m[k] = mk[u];
            }
            float ex[4];
#pragma unroll
            for (int k = 0; k < 4; ++k) ex[k] = __expf(cur_e[k]);

#pragma unroll
            for (int k = 0; k < 4; ++k) {
                const int s_idx = 4 * g + k;
                if (s_idx < Tn / 2 - 1) {     // 255 steps
                    // w_vec[j] = e_u[j] * beta[j]; broadcast via readlane.
                    const float wv = b_self * ex[k];
                    float au[Cn];
#pragma unroll
                    for (int i = 0; i < Cn; ++i)
                        au[i] = __int_as_float(
                            __builtin_amdgcn_readlane(__float_as_int(wv), i));

                    float acc0 = 0.f, acc1 = 0.f, acc2 = 0.f, acc3 = 0.f;
#pragma unroll
                    for (int i = 0; i < Cn; i += 4) {
                        acc0 = fmaf(au[i + 0], w[i + 0], acc0);
                        acc1 = fmaf(au[i + 1], w[i + 1], acc1);
                        acc2 = fmaf(au[i + 2], w[i + 2], acc2);
                        acc3 = fmaf(au[i + 3], w[i + 3], acc3);
                    }
                    float s = ((acc0 + acc1) + (acc2 + acc3));
                    if (!cur_m[k]) s = b_self;   // frozen step: beta carries
                    if (k == 3) {
                        const float mx = wave_max64(s);
                        s *= __builtin_amdgcn_rcpf(mx);
                        log_scale += __logf(mx);
                    }
                    b_self = s;
                }
            }
#pragma unroll
            for (int k = 0; k < 4; ++k) {
                cur_e[k] = nxt_e[k];
                cur_m[k] = nxt_m[k];
            }
        }

        ws_beta[bt * Cn + j] = b_self;        // beta_256
        if (j == 0) ws_lsB[bt] = log_scale;
    }
}

// Per chain: denom = lsF + lsB + log(sum_i alpha[i]*beta[i]); mean-reduce.
__global__ __launch_bounds__(64) void crf_combine_kernel(
    const float* __restrict__ ws_alpha,
    const float* __restrict__ ws_beta,
    const float* __restrict__ ws_lsF,
    const float* __restrict__ ws_lsB,
    const float* __restrict__ ws_num,
    float*       __restrict__ out)
{
    const int bt = blockIdx.x;
    const int j  = threadIdx.x;
    float v = ws_alpha[bt * Cn + j] * ws_beta[bt * Cn + j];
#pragma unroll
    for (int off = 32; off > 0; off >>= 1) v += __shfl_xor(v, off, 64);
    if (j == 0) {
        const float denom = ws_lsF[bt] + ws_lsB[bt] + __logf(v);
        atomicAdd(out, (denom - ws_num[bt]) * (1.0f / Bn));
    }
}

__global__ void crf_zero_kernel(float* out) { out[0] = 0.f; }

extern "C" void kernel_launch(void* const* d_in, const int* in_sizes, int n_in,
                              void* d_out, int out_size, void* d_ws, size_t ws_size,
                              hipStream_t stream)
{
    const float* emissions   = (const float*)d_in[0];
    const int*   tags        = (const int*)d_in[1];
    const int*   mask        = (const int*)d_in[2];
    const float* transitions = (const float*)d_in[3];
    const float* start_t     = (const float*)d_in[4];
    const float* end_t       = (const float*)d_in[5];

    float* ws       = (float*)d_ws;
    float* ws_alpha = ws;                       // 512*64
    float* ws_beta  = ws_alpha + Bn * Cn;       // 512*64
    float* ws_lsF   = ws_beta + Bn * Cn;        // 512
    float* ws_lsB   = ws_lsF + Bn;              // 512
    float* ws_num   = ws_lsB + Bn;              // 512

    crf_zero_kernel<<<1, 1, 0, stream>>>((float*)d_out);
    crf_half_kernel<<<2 * Bn, Cn, 0, stream>>>(emissions, tags, mask, transitions,
                                               start_t, end_t,
                                               ws_alpha, ws_beta, ws_lsF, ws_lsB, ws_num);
    crf_combine_kernel<<<Bn, Cn, 0, stream>>>(ws_alpha, ws_beta, ws_lsF, ws_lsB,
                                              ws_num, (float*)d_out);
}